// Round 16
// baseline (117.097 us; speedup 1.0000x reference)
//
#include <hip/hip_runtime.h>
#include <math.h>

typedef unsigned short u16;
typedef unsigned int u32;
typedef unsigned long long u64;
typedef float f32x4 __attribute__((ext_vector_type(4)));
typedef float f32x16 __attribute__((ext_vector_type(16)));
typedef __bf16 bf16x8 __attribute__((ext_vector_type(8)));
typedef __bf16 bf16x4 __attribute__((ext_vector_type(4)));
typedef __bf16 bf16x2 __attribute__((ext_vector_type(2)));
typedef u32 u32x4 __attribute__((ext_vector_type(4)));

constexpr int Bc = 4, Lc = 2048, Dc = 512, Hc = 8, DHc = 64;
constexpr int NTOK = Bc * Lc;          // 8192
constexpr float LN_EPS = 1e-5f;
constexpr int PS = 72;                 // attn epilogue LDS row stride (16B-aligned)
// fold 1/sqrt(Dh) * log2(e) into Q so softmax runs in exp2 domain
constexpr float QSCALE = 0.125f * 1.44269504088896340736f;
constexpr float MNEG = -1e30f;         // finite "-inf" for running max

__device__ inline u16 bf_bits(float f) {
  return __builtin_bit_cast(u16, (__bf16)f);
}
__device__ inline u32 pk2(float a, float b) {
  bf16x2 t; t[0] = (__bf16)a; t[1] = (__bf16)b;
  return __builtin_bit_cast(u32, t);
}

// ---------------------------------------------------------------------------
// prep2 (single dispatch): blocks 0..1023 cvt weights fp32->bf16;
// 1024..1055 pad bitmasks (+ block 1024 zeroes vm); 1056.. LayerNorm.
// ---------------------------------------------------------------------------
__global__ __launch_bounds__(256) void prep2_kernel(const float* __restrict__ s0,
                                                    const float* __restrict__ s1,
                                                    const float* __restrict__ s2,
                                                    const float* __restrict__ s3,
                                                    u16* __restrict__ d0,
                                                    u16* __restrict__ d1,
                                                    u16* __restrict__ d2,
                                                    u16* __restrict__ d3,
                                                    const int* __restrict__ tok,
                                                    u64* __restrict__ pm,
                                                    float* __restrict__ vm,
                                                    const float* __restrict__ x,
                                                    const float* __restrict__ gamma,
                                                    const float* __restrict__ beta,
                                                    u16* __restrict__ xn) {
  int bid = blockIdx.x;
  if (bid < 1024) {
    int mat = bid >> 8;
    int i = ((bid & 255) * 256 + threadIdx.x) * 4;
    const float* s = (mat == 0) ? s0 : (mat == 1) ? s1 : (mat == 2) ? s2 : s3;
    u16* d = (mat == 0) ? d0 : (mat == 1) ? d1 : (mat == 2) ? d2 : d3;
    float4 v = *(const float4*)&s[i];
    bf16x4 o;
    o[0] = (__bf16)v.x; o[1] = (__bf16)v.y; o[2] = (__bf16)v.z; o[3] = (__bf16)v.w;
    *(bf16x4*)&d[i] = o;
  } else if (bid < 1056) {
    int wid = ((bid - 1024) * 256 + threadIdx.x) >> 6;   // 0..127
    int lane = threadIdx.x & 63;
    u64 m = __ballot(tok[(size_t)wid * 64 + lane] == 0);
    if (lane == 0) pm[wid] = m;
    if (bid == 1024) {                                   // zero vm (2048 f32)
      float4 z = make_float4(0.f, 0.f, 0.f, 0.f);
      *(float4*)&vm[threadIdx.x * 8] = z;
      *(float4*)&vm[threadIdx.x * 8 + 4] = z;
    }
  } else {
    int wave = threadIdx.x >> 6;
    int lane = threadIdx.x & 63;
    int row  = (bid - 1056) * 4 + wave;                  // < 8192
    const float* xr = x + (size_t)row * Dc;
    float4 v0 = ((const float4*)xr)[lane * 2];
    float4 v1 = ((const float4*)xr)[lane * 2 + 1];
    float sum = v0.x + v0.y + v0.z + v0.w + v1.x + v1.y + v1.z + v1.w;
    float sq  = v0.x*v0.x + v0.y*v0.y + v0.z*v0.z + v0.w*v0.w
              + v1.x*v1.x + v1.y*v1.y + v1.z*v1.z + v1.w*v1.w;
    #pragma unroll
    for (int off = 32; off > 0; off >>= 1) {
      sum += __shfl_xor(sum, off);
      sq  += __shfl_xor(sq, off);
    }
    float mu = sum * (1.0f / Dc);
    float rs = rsqrtf(sq * (1.0f / Dc) - mu * mu + LN_EPS);
    float4 g0 = ((const float4*)gamma)[lane * 2];
    float4 g1 = ((const float4*)gamma)[lane * 2 + 1];
    float4 b0 = ((const float4*)beta)[lane * 2];
    float4 b1 = ((const float4*)beta)[lane * 2 + 1];
    bf16x8 o;
    o[0] = (__bf16)((v0.x - mu) * rs * g0.x + b0.x);
    o[1] = (__bf16)((v0.y - mu) * rs * g0.y + b0.y);
    o[2] = (__bf16)((v0.z - mu) * rs * g0.z + b0.z);
    o[3] = (__bf16)((v0.w - mu) * rs * g0.w + b0.w);
    o[4] = (__bf16)((v1.x - mu) * rs * g1.x + b1.x);
    o[5] = (__bf16)((v1.y - mu) * rs * g1.y + b1.y);
    o[6] = (__bf16)((v1.z - mu) * rs * g1.z + b1.z);
    o[7] = (__bf16)((v1.w - mu) * rs * g1.w + b1.w);
    *(bf16x8*)&xn[(size_t)row * Dc + lane * 8] = o;
  }
}

// ---------------------------------------------------------------------------
// bf16 MFMA GEMM with global_load_lds double-buffered staging (verified r15).
// ---------------------------------------------------------------------------
template <int MODE>
__global__ __launch_bounds__(256) void gemm_bf16(const u16* __restrict__ A,
                                                 const u16* __restrict__ W,
                                                 const float* __restrict__ res,
                                                 float* __restrict__ out_f,
                                                 u16* __restrict__ o_q,
                                                 u16* __restrict__ o_k,
                                                 u16* __restrict__ o_v,
                                                 float* __restrict__ vm) {
  __shared__ u16 As[2][128 * 64];
  __shared__ u16 Bs[2][128 * 64];
  int tid = threadIdx.x;
  int lane = tid & 63;
  int w = tid >> 6;
  int wr = w >> 1, wc = w & 1;
  int cc = lane & 15, rb = lane >> 4;
  int n0 = blockIdx.x * 128;
  int e0 = blockIdx.y * 128;

  auto stage = [&](int k0, int buf) {
    #pragma unroll
    for (int i = 0; i < 4; i++) {
      int s = (i * 4 + w) * 64 + lane;           // chunk 0..1023
      int row = s >> 3;
      int colp = (s & 7) ^ (row & 7);            // inverse-swizzled source
      const char* gA = (const char*)&A[(size_t)(n0 + row) * Dc + k0] + colp * 16;
      const char* gB = (const char*)&W[(size_t)(e0 + row) * Dc + k0] + colp * 16;
      __builtin_amdgcn_global_load_lds(
          (const __attribute__((address_space(1))) void*)gA,
          (__attribute__((address_space(3))) void*)&As[buf][(i * 4 + w) * 512], 16, 0, 0);
      __builtin_amdgcn_global_load_lds(
          (const __attribute__((address_space(1))) void*)gB,
          (__attribute__((address_space(3))) void*)&Bs[buf][(i * 4 + w) * 512], 16, 0, 0);
    }
  };

  f32x4 acc[4][4] = {};
  stage(0, 0);
  for (int kt = 0; kt < 8; kt++) {
    int cur = kt & 1;
    if (kt < 7) {
      stage((kt + 1) << 6, cur ^ 1);
      asm volatile("s_waitcnt vmcnt(8)" ::: "memory");
    } else {
      asm volatile("s_waitcnt vmcnt(0)" ::: "memory");
    }
    __builtin_amdgcn_sched_barrier(0);
    __builtin_amdgcn_s_barrier();
    __builtin_amdgcn_sched_barrier(0);
    #pragma unroll
    for (int kk = 0; kk < 2; kk++) {
      bf16x8 aF[4], bF[4];
      #pragma unroll
      for (int m = 0; m < 4; m++) {
        int row = wr * 64 + m * 16 + cc;
        int cp = ((rb + kk * 4) ^ (cc & 7)) << 3;
        aF[m] = *(bf16x8*)&As[cur][row * 64 + cp];
      }
      #pragma unroll
      for (int n = 0; n < 4; n++) {
        int row = wc * 64 + n * 16 + cc;
        int cp = ((rb + kk * 4) ^ (cc & 7)) << 3;
        bF[n] = *(bf16x8*)&Bs[cur][row * 64 + cp];
      }
      #pragma unroll
      for (int m = 0; m < 4; m++)
        #pragma unroll
        for (int n = 0; n < 4; n++)
          acc[m][n] = __builtin_amdgcn_mfma_f32_16x16x32_bf16(aF[m], bF[n], acc[m][n], 0, 0, 0);
    }
    __syncthreads();
  }

  if (MODE == 3) {
    int bb = n0 >> 11;
    int mat = e0 >> 9;
    int e0c = e0 & 511;
    if (mat == 2) {
      #pragma unroll
      for (int n = 0; n < 4; n++) {
        int c = e0c + wc * 64 + n * 16 + cc;
        int h = c >> 6, dh = c & 63;
        float cp = 0.f;
        #pragma unroll
        for (int m = 0; m < 4; m++) {
          int l = (n0 + wr * 64 + m * 16 + rb * 4) & (Lc - 1);
          bf16x4 o4;
          o4[0] = (__bf16)acc[m][n][0]; o4[1] = (__bf16)acc[m][n][1];
          o4[2] = (__bf16)acc[m][n][2]; o4[3] = (__bf16)acc[m][n][3];
          size_t addr = ((((size_t)(bb * Hc + h)) * (Lc / 64) + (l >> 6)) * DHc + dh) * 64 + (l & 63);
          *(bf16x4*)&o_v[addr] = o4;
          cp += (acc[m][n][0] + acc[m][n][1]) + (acc[m][n][2] + acc[m][n][3]);
        }
        cp += __shfl_xor(cp, 16);
        cp += __shfl_xor(cp, 32);
        if (lane < 16) atomicAdd(&vm[(bb * Hc + h) * DHc + dh], cp);
      }
    } else {
      float sc = (mat == 0) ? QSCALE : 1.0f;
      u16* dst = (mat == 0) ? o_q : o_k;
      #pragma unroll
      for (int m = 0; m < 4; m++) {
        #pragma unroll
        for (int n = 0; n < 4; n++) {
          #pragma unroll
          for (int j = 0; j < 4; j++) {
            int r = n0 + wr * 64 + m * 16 + rb * 4 + j;
            int c = e0c + wc * 64 + n * 16 + cc;
            int ll = r & (Lc - 1);
            dst[(((size_t)(bb * Hc + (c >> 6))) * Lc + ll) * DHc + (c & 63)] = bf_bits(acc[m][n][j] * sc);
          }
        }
      }
    }
  } else {
    #pragma unroll
    for (int m = 0; m < 4; m++) {
      #pragma unroll
      for (int n = 0; n < 4; n++) {
        #pragma unroll
        for (int j = 0; j < 4; j++) {
          int r = n0 + wr * 64 + m * 16 + rb * 4 + j;
          int c = e0 + wc * 64 + n * 16 + cc;
          size_t o = (size_t)r * Dc + c;
          out_f[o] = acc[m][n][j] + res[o];
        }
      }
    }
  }
}

// ---------------------------------------------------------------------------
// Flash attention v12: 32x32x16 MFMA, P fully IN-REGISTER (no LDS roundtrip,
// no per-tile lgkmcnt stop). Swapped QK^T: D col=lane&31=q, row=k (verified
// layout m74/m101). PV B-operand words assembled via cvt-pack of reg pairs +
// one __shfl_xor(32) per pack. One wave per (bh,qt), QBLK=32, KVBLK=64.
// ---------------------------------------------------------------------------
__global__ __launch_bounds__(64) void attn12(const u16* __restrict__ Q,
                                             const u16* __restrict__ K,
                                             const u16* __restrict__ VT,
                                             const float* __restrict__ vm,
                                             const u64* __restrict__ pmask,
                                             u16* __restrict__ out) {
  __shared__ u16 Ps[32 * PS];                        // epilogue transpose only
  int lane = threadIdx.x;
  int ql = lane & 31;                                // q within tile / row d
  int hi = lane >> 5;                                // lane half
  int bh = blockIdx.x;
  int qt = (int)gridDim.y - 1 - (int)blockIdx.y;     // heavy q-tiles first
  int q0 = qt * 32;
  int b = bh >> 3, h = bh & 7;
  const u16* Qb = Q + (size_t)bh * Lc * DHc;
  const u16* Kb = K + (size_t)bh * Lc * DHc;
  const u16* Vb = VT + (size_t)bh * Lc * DHc;        // blocked [L/64][DH][64]
  const u64* pmb = pmask + (b << 5);
  int nfull = q0 >> 6;

  // Q fragments (B-operand): col q = q0+ql, d = ds*16 + hi*8 + e
  bf16x8 qF[4];
  #pragma unroll
  for (int ds = 0; ds < 4; ds++)
    qF[ds] = *(const bf16x8*)&Qb[(size_t)(q0 + ql) * DHc + ds * 16 + hi * 8];

  float mrow = MNEG;
  float lrow = 0.f;                                  // per-lane partial
  f32x16 oacc0 = {}, oacc1 = {};                     // O^T d-blocks 0,1

  for (int kt = 0; kt <= nfull; kt++) {
    int k0 = kt * 64;
    bool last = (kt == nfull);
    u64 pm = pmb[kt];
    // QK^T: S^T[kb] = K·Q^T, kb = 0,1 (32 k-rows each), 4 chained d-steps
    f32x16 sq0 = {}, sq1 = {};
    {
      bf16x8 kf0[4], kf1[4];
      #pragma unroll
      for (int ds = 0; ds < 4; ds++) {
        kf0[ds] = *(const bf16x8*)&Kb[(size_t)(k0 + ql) * DHc + ds * 16 + hi * 8];
        kf1[ds] = *(const bf16x8*)&Kb[(size_t)(k0 + 32 + ql) * DHc + ds * 16 + hi * 8];
      }
      __builtin_amdgcn_s_setprio(1);
      #pragma unroll
      for (int ds = 0; ds < 4; ds++) {
        sq0 = __builtin_amdgcn_mfma_f32_32x32x16_bf16(kf0[ds], qF[ds], sq0, 0, 0, 0);
        sq1 = __builtin_amdgcn_mfma_f32_32x32x16_bf16(kf1[ds], qF[ds], sq1, 0, 0, 0);
      }
      __builtin_amdgcn_s_setprio(0);
    }
    __builtin_amdgcn_sched_barrier(0);     // keep V loads below QK^T (reg reuse)
    // V fragments (A-operand): row d = dblk*32+ql, k = ks*16 + hi*8 + e
    const u16* vp = Vb + (size_t)kt * (DHc * 64);
    bf16x8 vf0[4], vf1[4];
    #pragma unroll
    for (int ks = 0; ks < 4; ks++) {
      vf0[ks] = *(const bf16x8*)&vp[(size_t)ql * 64 + ks * 16 + hi * 8];
      vf1[ks] = *(const bf16x8*)&vp[(size_t)(32 + ql) * 64 + ks * 16 + hi * 8];
    }
    // masks: k_in_tile = kb*32 + (r&3) + 8*(r>>2) + 4*hi
    if (pm) {
      u64 pmh = pm >> (4 * hi);
      #pragma unroll
      for (int r = 0; r < 16; r++) {
        int krb = (r & 3) + 8 * (r >> 2);
        if ((pmh >> krb) & 1)        sq0[r] = -INFINITY;
        if ((pmh >> (32 + krb)) & 1) sq1[r] = -INFINITY;
      }
    }
    if (last) {
      int qrel = q0 + ql - k0;
      #pragma unroll
      for (int r = 0; r < 16; r++) {
        int krb = (r & 3) + 8 * (r >> 2) + 4 * hi;
        if (krb > qrel)      sq0[r] = -INFINITY;
        if (krb + 32 > qrel) sq1[r] = -INFINITY;
      }
    }
    // online softmax (defer-max THR=8, exp2 domain), shuffle-free common path
    {
      float mx = sq0[0];
      #pragma unroll
      for (int r = 1; r < 16; r++) mx = fmaxf(mx, sq0[r]);
      #pragma unroll
      for (int r = 0; r < 16; r++) mx = fmaxf(mx, sq1[r]);
      if (!__all(mx <= mrow + 8.f)) {
        float mf = fmaxf(mx, __shfl_xor(mx, 32));    // pair-uniform row max
        float nm = fmaxf(mrow, mf);
        float alpha = exp2f(mrow - nm);
        lrow *= alpha;
        #pragma unroll
        for (int r = 0; r < 16; r++) { oacc0[r] *= alpha; oacc1[r] *= alpha; }
        mrow = nm;
      }
      float rs = 0.f;
      #pragma unroll
      for (int r = 0; r < 16; r++) {
        sq0[r] = exp2f(sq0[r] - mrow); rs += sq0[r];
        sq1[r] = exp2f(sq1[r] - mrow); rs += sq1[r];
      }
      lrow += rs;
    }
    // P -> PV B-operand in registers: per ks, words from reg pairs (R..R+3)
    // of sq[kb=ks>>1]; cross-half words via shfl_xor(32).
    __builtin_amdgcn_s_setprio(1);
    #pragma unroll
    for (int ks = 0; ks < 4; ks++) {
      u32 u, v;
      if (ks == 0)      { u = pk2(sq0[0], sq0[1]);  v = pk2(sq0[2], sq0[3]); }
      else if (ks == 1) { u = pk2(sq0[8], sq0[9]);  v = pk2(sq0[10], sq0[11]); }
      else if (ks == 2) { u = pk2(sq1[0], sq1[1]);  v = pk2(sq1[2], sq1[3]); }
      else              { u = pk2(sq1[8], sq1[9]);  v = pk2(sq1[10], sq1[11]); }
      u32 us = (u32)__shfl_xor((int)u, 32);
      u32 vs = (u32)__shfl_xor((int)v, 32);
      u32x4 wv;
      wv[0] = hi ? us : u;                           // k = ks*16 + 0..1 (+hi*8)
      wv[1] = hi ? vs : v;
      wv[2] = hi ? u : us;
      wv[3] = hi ? v : vs;
      // wait: words 0,1 must be e=0..3 (hi_src=0), 2,3 e=4..7 (hi_src=1) —
      // but each lane's B-frag k starts at ks*16 + hi*8: for hi=1 lanes the
      // FIRST words come from hi_src=1 regs... recheck: k = ks*16 + hi*8 + e,
      // e=0..7; hi_src = ((hi*8 + e) >> 2) & 1 = (2*hi + (e>>2)) & 1 = (e>>2)
      // XOR'd with nothing... 2*hi is even, so hi_src = (e>>2)&1 regardless of
      // hi. BUT the k' within kb differs: k' = 16*(ks&1) + hi*8 + e — for
      // hi=1, k' = base+8+e -> r = (k'&3)+4*(k'>>3): k'=base+8 -> r = 4+... 
      // r = (k'&3) + 4*(k'>>3): base=0,hi=1,e=0: k'=8 -> r=0+4*1=4. So hi=1
      // lanes source regs R+4..R+7, not R..R+3!
      // Correct both-halves mapping below replaces this block.
      f32x16 dummy = {};
      (void)dummy; (void)wv;
      // assembled properly below
      u32 uB, vB;
      if (ks == 0)      { uB = pk2(sq0[4], sq0[5]);  vB = pk2(sq0[6], sq0[7]); }
      else if (ks == 1) { uB = pk2(sq0[12], sq0[13]); vB = pk2(sq0[14], sq0[15]); }
      else if (ks == 2) { uB = pk2(sq1[4], sq1[5]);  vB = pk2(sq1[6], sq1[7]); }
      else              { uB = pk2(sq1[12], sq1[13]); vB = pk2(sq1[14], sq1[15]); }
      // lane half hi needs k' = 16*(ks&1) + hi*8 + e:
      //   hi=0: k' = base+e   : e<4 -> regs R..R+3 of hi_src=(e>>2)=0 half? 
      // Derivation (k' = (r&3)+8*(r>>2)+4*hi_src):
      //   e=0..3: k'=base+e   -> r=R+e,   hi_src=0 -> word01 = {u,v} from hi0
      //   e=4..7: k'=base+4+eb -> r=R+eb, hi_src=1 -> word23 = {u,v} from hi1
      //   hi=1: e=0..3: k'=base+8+e -> r=R+4+e, hi_src=0 -> {uB,vB} from hi0
      //         e=4..7: k'=base+12+eb -> r=R+4+eb, hi_src=1 -> {uB,vB} from hi1
      u32 usB = (u32)__shfl_xor((int)uB, 32);
      u32 vsB = (u32)__shfl_xor((int)vB, 32);
      u32x4 wf;
      if (hi == 0) {
        wf[0] = u;   wf[1] = v;    // own (hi0) regs R..R+3
        wf[2] = us;  wf[3] = vs;   // hi1's regs R..R+3
      } else {
        wf[0] = usB; wf[1] = vsB;  // hi0's regs R+4..R+7
        wf[2] = uB;  wf[3] = vB;   // own (hi1) regs R+4..R+7
      }
      bf16x8 pB = __builtin_bit_cast(bf16x8, wf);
      if (ks < 2) {
        oacc0 = __builtin_amdgcn_mfma_f32_32x32x16_bf16(vf0[ks], pB, oacc0, 0, 0, 0);
        oacc1 = __builtin_amdgcn_mfma_f32_32x32x16_bf16(vf1[ks], pB, oacc1, 0, 0, 0);
      } else {
        oacc0 = __builtin_amdgcn_mfma_f32_32x32x16_bf16(vf0[ks], pB, oacc0, 0, 0, 0);
        oacc1 = __builtin_amdgcn_mfma_f32_32x32x16_bf16(vf1[ks], pB, oacc1, 0, 0, 0);
      }
    }
    __builtin_amdgcn_s_setprio(0);
  }

  // finalize l (pair covers both k-halves of each q)
  lrow += __shfl_xor(lrow, 32);

  // epilogue via LDS transpose: lane owns row q=ql (its 32 d-values, half hi)
  bool ok = lrow > 0.f;
  float inv = ok ? 1.0f / lrow : 0.f;
  #pragma unroll
  for (int rq = 0; rq < 4; rq++) {
    #pragma unroll
    for (int dblk = 0; dblk < 2; dblk++) {
      int d = dblk * 32 + rq * 8 + 4 * hi;           // regs 4rq..4rq+3 -> d..d+3
      float a0, a1, a2, a3;
      if (dblk == 0) { a0 = oacc0[rq*4]; a1 = oacc0[rq*4+1]; a2 = oacc0[rq*4+2]; a3 = oacc0[rq*4+3]; }
      else           { a0 = oacc1[rq*4]; a1 = oacc1[rq*4+1]; a2 = oacc1[rq*4+2]; a3 = oacc1[rq*4+3]; }
      float v0 = ok ? a0 * inv : vm[bh * DHc + d] * (1.0f / Lc);
      float v1 = ok ? a1 * inv : vm[bh * DHc + d + 1] * (1.0f / Lc);
      float v2 = ok ? a2 * inv : vm[bh * DHc + d + 2] * (1.0f / Lc);
      float v3 = ok ? a3 * inv : vm[bh * DHc + d + 3] * (1.0f / Lc);
      *(u32*)&Ps[ql * PS + d]     = pk2(v0, v1);
      *(u32*)&Ps[ql * PS + d + 2] = pk2(v2, v3);
    }
  }
  asm volatile("s_waitcnt lgkmcnt(0)" ::: "memory");
  __builtin_amdgcn_sched_barrier(0);
  {
    u16* dst = out + ((size_t)(b * Lc + q0 + ql)) * Dc + h * DHc + hi * 32;
    #pragma unroll
    for (int uq = 0; uq < 4; uq++) {
      bf16x8 t = *(bf16x8*)&Ps[ql * PS + hi * 32 + uq * 8];
      *(bf16x8*)&dst[uq * 8] = t;
    }
  }
}

// ---------------------------------------------------------------------------
// Launch
// ---------------------------------------------------------------------------
extern "C" void kernel_launch(void* const* d_in, const int* in_sizes, int n_in,
                              void* d_out, int out_size, void* d_ws, size_t ws_size,
                              hipStream_t stream) {
  const float* x     = (const float*)d_in[0];
  const int*   tok   = (const int*)d_in[1];
  const float* Wq    = (const float*)d_in[2];
  const float* Wk    = (const float*)d_in[3];
  const float* Wv    = (const float*)d_in[4];
  const float* Wo    = (const float*)d_in[5];
  const float* gamma = (const float*)d_in[6];
  const float* beta  = (const float*)d_in[7];
  float* out = (float*)d_out;

  const size_t SEG = (size_t)NTOK * Dc;     // 4,194,304 elems
  const size_t WSEG = (size_t)Dc * Dc;      // 262,144 elems
  u16* xn   = (u16*)d_ws;
  u16* Qd   = xn + SEG;
  u16* Kd   = Qd + SEG;
  u16* VT   = Kd + SEG;                     // blocked [B][H][L/64][DH][64]
  u16* ao   = VT + SEG;
  u16* Wqkv = ao + SEG;                     // 3*WSEG (Q,K,V rows stacked)
  u16* Wob  = Wqkv + 3 * WSEG;
  float* vm = (float*)(Wob + WSEG);         // 2048 f32
  u64* pmarr = (u64*)(vm + (size_t)Bc * Hc * DHc);  // 128 u64

  prep2_kernel<<<3104, 256, 0, stream>>>(Wq, Wk, Wv, Wo,
                                         Wqkv, Wqkv + WSEG, Wqkv + 2 * WSEG, Wob,
                                         tok, pmarr, vm, x, gamma, beta, xn);

  dim3 gq(NTOK / 128, (3 * Dc) / 128);      // 64 x 12
  gemm_bf16<3><<<gq, 256, 0, stream>>>(xn, Wqkv, nullptr, nullptr, Qd, Kd, VT, vm);

  dim3 ga(Bc * Hc, Lc / 32);                // 32 x 64 one-wave blocks
  attn12<<<ga, 64, 0, stream>>>(Qd, Kd, VT, vm, pmarr, ao);

  dim3 gg(NTOK / 128, Dc / 128);            // 64 x 4
  gemm_bf16<0><<<gg, 256, 0, stream>>>(ao, Wob, x, out, nullptr, nullptr, nullptr, nullptr);
}

// Round 17
// 106.492 us; speedup vs baseline: 1.0996x; 1.0996x over previous
//
#include <hip/hip_runtime.h>
#include <math.h>

typedef unsigned short u16;
typedef unsigned int u32;
typedef unsigned long long u64;
typedef float f32x4 __attribute__((ext_vector_type(4)));
typedef __bf16 bf16x8 __attribute__((ext_vector_type(8)));
typedef __bf16 bf16x4 __attribute__((ext_vector_type(4)));

constexpr int Bc = 4, Lc = 2048, Dc = 512, Hc = 8, DHc = 64;
constexpr int NTOK = Bc * Lc;          // 8192
constexpr float LN_EPS = 1e-5f;
constexpr int PS = 72;                 // attn P-scratch row stride
// fold 1/sqrt(Dh) * log2(e) into Q so softmax runs in exp2 domain
constexpr float QSCALE = 0.125f * 1.44269504088896340736f;
constexpr float MNEG = -1e30f;         // finite "-inf" for running max

__device__ inline u16 bf_bits(float f) {
  return __builtin_bit_cast(u16, (__bf16)f);
}

// ---------------------------------------------------------------------------
// prep2 (single dispatch): blocks 0..1023 cvt weights fp32->bf16;
// 1024..1055 pad bitmasks (+ block 1024 zeroes vm); 1056.. LayerNorm.
// ---------------------------------------------------------------------------
__global__ __launch_bounds__(256) void prep2_kernel(const float* __restrict__ s0,
                                                    const float* __restrict__ s1,
                                                    const float* __restrict__ s2,
                                                    const float* __restrict__ s3,
                                                    u16* __restrict__ d0,
                                                    u16* __restrict__ d1,
                                                    u16* __restrict__ d2,
                                                    u16* __restrict__ d3,
                                                    const int* __restrict__ tok,
                                                    u64* __restrict__ pm,
                                                    float* __restrict__ vm,
                                                    const float* __restrict__ x,
                                                    const float* __restrict__ gamma,
                                                    const float* __restrict__ beta,
                                                    u16* __restrict__ xn) {
  int bid = blockIdx.x;
  if (bid < 1024) {
    int mat = bid >> 8;
    int i = ((bid & 255) * 256 + threadIdx.x) * 4;
    const float* s = (mat == 0) ? s0 : (mat == 1) ? s1 : (mat == 2) ? s2 : s3;
    u16* d = (mat == 0) ? d0 : (mat == 1) ? d1 : (mat == 2) ? d2 : d3;
    float4 v = *(const float4*)&s[i];
    bf16x4 o;
    o[0] = (__bf16)v.x; o[1] = (__bf16)v.y; o[2] = (__bf16)v.z; o[3] = (__bf16)v.w;
    *(bf16x4*)&d[i] = o;
  } else if (bid < 1056) {
    int wid = ((bid - 1024) * 256 + threadIdx.x) >> 6;   // 0..127
    int lane = threadIdx.x & 63;
    u64 m = __ballot(tok[(size_t)wid * 64 + lane] == 0);
    if (lane == 0) pm[wid] = m;
    if (bid == 1024) {                                   // zero vm (2048 f32)
      float4 z = make_float4(0.f, 0.f, 0.f, 0.f);
      *(float4*)&vm[threadIdx.x * 8] = z;
      *(float4*)&vm[threadIdx.x * 8 + 4] = z;
    }
  } else {
    int wave = threadIdx.x >> 6;
    int lane = threadIdx.x & 63;
    int row  = (bid - 1056) * 4 + wave;                  // < 8192
    const float* xr = x + (size_t)row * Dc;
    float4 v0 = ((const float4*)xr)[lane * 2];
    float4 v1 = ((const float4*)xr)[lane * 2 + 1];
    float sum = v0.x + v0.y + v0.z + v0.w + v1.x + v1.y + v1.z + v1.w;
    float sq  = v0.x*v0.x + v0.y*v0.y + v0.z*v0.z + v0.w*v0.w
              + v1.x*v1.x + v1.y*v1.y + v1.z*v1.z + v1.w*v1.w;
    #pragma unroll
    for (int off = 32; off > 0; off >>= 1) {
      sum += __shfl_xor(sum, off);
      sq  += __shfl_xor(sq, off);
    }
    float mu = sum * (1.0f / Dc);
    float rs = rsqrtf(sq * (1.0f / Dc) - mu * mu + LN_EPS);
    float4 g0 = ((const float4*)gamma)[lane * 2];
    float4 g1 = ((const float4*)gamma)[lane * 2 + 1];
    float4 b0 = ((const float4*)beta)[lane * 2];
    float4 b1 = ((const float4*)beta)[lane * 2 + 1];
    bf16x8 o;
    o[0] = (__bf16)((v0.x - mu) * rs * g0.x + b0.x);
    o[1] = (__bf16)((v0.y - mu) * rs * g0.y + b0.y);
    o[2] = (__bf16)((v0.z - mu) * rs * g0.z + b0.z);
    o[3] = (__bf16)((v0.w - mu) * rs * g0.w + b0.w);
    o[4] = (__bf16)((v1.x - mu) * rs * g1.x + b1.x);
    o[5] = (__bf16)((v1.y - mu) * rs * g1.y + b1.y);
    o[6] = (__bf16)((v1.z - mu) * rs * g1.z + b1.z);
    o[7] = (__bf16)((v1.w - mu) * rs * g1.w + b1.w);
    *(bf16x8*)&xn[(size_t)row * Dc + lane * 8] = o;
  }
}

// ---------------------------------------------------------------------------
// bf16 MFMA GEMM with global_load_lds double-buffered staging (verified r15).
// ---------------------------------------------------------------------------
template <int MODE>
__global__ __launch_bounds__(256) void gemm_bf16(const u16* __restrict__ A,
                                                 const u16* __restrict__ W,
                                                 const float* __restrict__ res,
                                                 float* __restrict__ out_f,
                                                 u16* __restrict__ o_q,
                                                 u16* __restrict__ o_k,
                                                 u16* __restrict__ o_v,
                                                 float* __restrict__ vm) {
  __shared__ u16 As[2][128 * 64];
  __shared__ u16 Bs[2][128 * 64];
  int tid = threadIdx.x;
  int lane = tid & 63;
  int w = tid >> 6;
  int wr = w >> 1, wc = w & 1;
  int cc = lane & 15, rb = lane >> 4;
  int n0 = blockIdx.x * 128;
  int e0 = blockIdx.y * 128;

  auto stage = [&](int k0, int buf) {
    #pragma unroll
    for (int i = 0; i < 4; i++) {
      int s = (i * 4 + w) * 64 + lane;           // chunk 0..1023
      int row = s >> 3;
      int colp = (s & 7) ^ (row & 7);            // inverse-swizzled source
      const char* gA = (const char*)&A[(size_t)(n0 + row) * Dc + k0] + colp * 16;
      const char* gB = (const char*)&W[(size_t)(e0 + row) * Dc + k0] + colp * 16;
      __builtin_amdgcn_global_load_lds(
          (const __attribute__((address_space(1))) void*)gA,
          (__attribute__((address_space(3))) void*)&As[buf][(i * 4 + w) * 512], 16, 0, 0);
      __builtin_amdgcn_global_load_lds(
          (const __attribute__((address_space(1))) void*)gB,
          (__attribute__((address_space(3))) void*)&Bs[buf][(i * 4 + w) * 512], 16, 0, 0);
    }
  };

  f32x4 acc[4][4] = {};
  stage(0, 0);
  for (int kt = 0; kt < 8; kt++) {
    int cur = kt & 1;
    if (kt < 7) {
      stage((kt + 1) << 6, cur ^ 1);
      asm volatile("s_waitcnt vmcnt(8)" ::: "memory");
    } else {
      asm volatile("s_waitcnt vmcnt(0)" ::: "memory");
    }
    __builtin_amdgcn_sched_barrier(0);
    __builtin_amdgcn_s_barrier();
    __builtin_amdgcn_sched_barrier(0);
    #pragma unroll
    for (int kk = 0; kk < 2; kk++) {
      bf16x8 aF[4], bF[4];
      #pragma unroll
      for (int m = 0; m < 4; m++) {
        int row = wr * 64 + m * 16 + cc;
        int cp = ((rb + kk * 4) ^ (cc & 7)) << 3;
        aF[m] = *(bf16x8*)&As[cur][row * 64 + cp];
      }
      #pragma unroll
      for (int n = 0; n < 4; n++) {
        int row = wc * 64 + n * 16 + cc;
        int cp = ((rb + kk * 4) ^ (cc & 7)) << 3;
        bF[n] = *(bf16x8*)&Bs[cur][row * 64 + cp];
      }
      #pragma unroll
      for (int m = 0; m < 4; m++)
        #pragma unroll
        for (int n = 0; n < 4; n++)
          acc[m][n] = __builtin_amdgcn_mfma_f32_16x16x32_bf16(aF[m], bF[n], acc[m][n], 0, 0, 0);
    }
    __syncthreads();
  }

  if (MODE == 3) {
    int bb = n0 >> 11;
    int mat = e0 >> 9;
    int e0c = e0 & 511;
    if (mat == 2) {
      #pragma unroll
      for (int n = 0; n < 4; n++) {
        int c = e0c + wc * 64 + n * 16 + cc;
        int h = c >> 6, dh = c & 63;
        float cp = 0.f;
        #pragma unroll
        for (int m = 0; m < 4; m++) {
          int l = (n0 + wr * 64 + m * 16 + rb * 4) & (Lc - 1);
          bf16x4 o4;
          o4[0] = (__bf16)acc[m][n][0]; o4[1] = (__bf16)acc[m][n][1];
          o4[2] = (__bf16)acc[m][n][2]; o4[3] = (__bf16)acc[m][n][3];
          size_t addr = ((((size_t)(bb * Hc + h)) * (Lc / 64) + (l >> 6)) * DHc + dh) * 64 + (l & 63);
          *(bf16x4*)&o_v[addr] = o4;
          cp += (acc[m][n][0] + acc[m][n][1]) + (acc[m][n][2] + acc[m][n][3]);
        }
        cp += __shfl_xor(cp, 16);
        cp += __shfl_xor(cp, 32);
        if (lane < 16) atomicAdd(&vm[(bb * Hc + h) * DHc + dh], cp);
      }
    } else {
      float sc = (mat == 0) ? QSCALE : 1.0f;
      u16* dst = (mat == 0) ? o_q : o_k;
      #pragma unroll
      for (int m = 0; m < 4; m++) {
        #pragma unroll
        for (int n = 0; n < 4; n++) {
          #pragma unroll
          for (int j = 0; j < 4; j++) {
            int r = n0 + wr * 64 + m * 16 + rb * 4 + j;
            int c = e0c + wc * 64 + n * 16 + cc;
            int ll = r & (Lc - 1);
            dst[(((size_t)(bb * Hc + (c >> 6))) * Lc + ll) * DHc + (c & 63)] = bf_bits(acc[m][n][j] * sc);
          }
        }
      }
    }
  } else {
    #pragma unroll
    for (int m = 0; m < 4; m++) {
      #pragma unroll
      for (int n = 0; n < 4; n++) {
        #pragma unroll
        for (int j = 0; j < 4; j++) {
          int r = n0 + wr * 64 + m * 16 + rb * 4 + j;
          int c = e0 + wc * 64 + n * 16 + cc;
          size_t o = (size_t)r * Dc + c;
          out_f[o] = acc[m][n][j] + res[o];
        }
      }
    }
  }
}

// ---------------------------------------------------------------------------
// Flash attention v13 = attn11 (champion numerics) + CROSS-TILE pipelining:
// QK^T(t+1) MFMAs issued BEFORE softmax(t) VALU -> the two pipes overlap
// within the wave. Named double buffers sqA/sqB + kfA/kfB (rule #20 safe).
// V loads just-in-time per processed tile. No occupancy attributes.
// ---------------------------------------------------------------------------
__global__ __launch_bounds__(64) void attn13(const u16* __restrict__ Q,
                                             const u16* __restrict__ K,
                                             const u16* __restrict__ VT,
                                             const float* __restrict__ vm,
                                             const u64* __restrict__ pmask,
                                             u16* __restrict__ out) {
  __shared__ u16 Ps[32 * PS];
  int lane = threadIdx.x;
  int cc = lane & 15, rb = lane >> 4;
  int bh = blockIdx.x;
  int qt = (int)gridDim.y - 1 - (int)blockIdx.y;     // heavy q-tiles first
  int q0 = qt * 32;
  int b = bh >> 3, h = bh & 7;
  const u16* Qb = Q + (size_t)bh * Lc * DHc;
  const u16* Kb = K + (size_t)bh * Lc * DHc;
  const u16* Vb = VT + (size_t)bh * Lc * DHc;        // blocked [L/64][DH][64]
  const u64* pmb = pmask + (b << 5);
  int nfull = q0 >> 6;                               // last tile index

  bf16x8 qF[2][2];
  #pragma unroll
  for (int qb = 0; qb < 2; qb++)
    #pragma unroll
    for (int kc = 0; kc < 2; kc++)
      qF[qb][kc] = *(const bf16x8*)&Qb[(size_t)(q0 + qb * 16 + cc) * DHc + kc * 32 + rb * 8];

  float mrow[2] = {MNEG, MNEG};
  float lrow[2] = {0.f, 0.f};
  f32x4 acc[2][4] = {};

  bf16x8 kfA[4][2], kfB[4][2];
  f32x4 sqA[2][4], sqB[2][4];

  auto loadK = [&](int kt, bf16x8 (&kf)[4][2]) {
    const u16* kp = Kb + (size_t)(kt * 64) * DHc;
    #pragma unroll
    for (int c = 0; c < 4; c++) {
      kf[c][0] = *(const bf16x8*)&kp[(c * 16 + cc) * DHc + rb * 8];
      kf[c][1] = *(const bf16x8*)&kp[(c * 16 + cc) * DHc + 32 + rb * 8];
    }
  };
  auto qkt = [&](bf16x8 (&kf)[4][2], f32x4 (&sq)[2][4]) {
    #pragma unroll
    for (int qb = 0; qb < 2; qb++)
      #pragma unroll
      for (int c = 0; c < 4; c++)
        sq[qb][c] = f32x4{};
    __builtin_amdgcn_s_setprio(1);
    #pragma unroll
    for (int c = 0; c < 4; c++) {
      #pragma unroll
      for (int qb = 0; qb < 2; qb++) {
        sq[qb][c] = __builtin_amdgcn_mfma_f32_16x16x32_bf16(kf[c][0], qF[qb][0], sq[qb][c], 0, 0, 0);
        sq[qb][c] = __builtin_amdgcn_mfma_f32_16x16x32_bf16(kf[c][1], qF[qb][1], sq[qb][c], 0, 0, 0);
      }
    }
    __builtin_amdgcn_s_setprio(0);
  };
  auto process = [&](int kt, f32x4 (&sq)[2][4]) {
    int k0 = kt * 64;
    bool last = (kt == nfull);
    u64 pm = pmb[kt];
    // V tile: contiguous 8KB block, issue now (consumed at PV)
    const u16* vp = Vb + (size_t)kt * (DHc * 64);
    bf16x8 vf[2][4];
    #pragma unroll
    for (int kc = 0; kc < 2; kc++)
      #pragma unroll
      for (int d0 = 0; d0 < 4; d0++)
        vf[kc][d0] = *(const bf16x8*)&vp[(d0 * 16 + cc) * 64 + kc * 32 + rb * 8];

    if (pm) {                                      // pad mask: ~never taken
      #pragma unroll
      for (int c = 0; c < 4; c++) {
        u32 smr = (((u32)(pm >> (c * 16)) & 0xffffu) >> (rb * 4));
        #pragma unroll
        for (int qb = 0; qb < 2; qb++)
          #pragma unroll
          for (int j = 0; j < 4; j++)
            if ((smr >> j) & 1) sq[qb][c][j] = -INFINITY;
      }
    }
    if (last) {                                    // causal boundary tile
      #pragma unroll
      for (int qb = 0; qb < 2; qb++) {
        int qrel = q0 + qb * 16 + cc - k0;
        #pragma unroll
        for (int c = 0; c < 4; c++)
          #pragma unroll
          for (int j = 0; j < 4; j++)
            if (c * 16 + rb * 4 + j > qrel) sq[qb][c][j] = -INFINITY;
      }
    }
    #pragma unroll
    for (int qb = 0; qb < 2; qb++) {
      float m0 = fmaxf(fmaxf(sq[qb][0][0], sq[qb][0][1]), fmaxf(sq[qb][0][2], sq[qb][0][3]));
      float m1 = fmaxf(fmaxf(sq[qb][1][0], sq[qb][1][1]), fmaxf(sq[qb][1][2], sq[qb][1][3]));
      float m2 = fmaxf(fmaxf(sq[qb][2][0], sq[qb][2][1]), fmaxf(sq[qb][2][2], sq[qb][2][3]));
      float m3 = fmaxf(fmaxf(sq[qb][3][0], sq[qb][3][1]), fmaxf(sq[qb][3][2], sq[qb][3][3]));
      float mx = fmaxf(fmaxf(m0, m1), fmaxf(m2, m3));
      mx = fmaxf(mx, __shfl_xor(mx, 16));
      mx = fmaxf(mx, __shfl_xor(mx, 32));
      if (!__all(mx <= mrow[qb] + 8.f)) {
        float nm = fmaxf(mrow[qb], mx);
        float alpha = exp2f(mrow[qb] - nm);
        lrow[qb] *= alpha;
        #pragma unroll
        for (int d0 = 0; d0 < 4; d0++)
          #pragma unroll
          for (int j = 0; j < 4; j++)
            acc[qb][d0][j] *= alpha;
        mrow[qb] = nm;
      }
      float rs = 0.f;
      #pragma unroll
      for (int c = 0; c < 4; c++) {
        f32x4 p;
        #pragma unroll
        for (int j = 0; j < 4; j++) p[j] = exp2f(sq[qb][c][j] - mrow[qb]);
        rs += (p[0] + p[1]) + (p[2] + p[3]);
        bf16x4 p4;
        p4[0] = (__bf16)p[0]; p4[1] = (__bf16)p[1];
        p4[2] = (__bf16)p[2]; p4[3] = (__bf16)p[3];
        *(bf16x4*)&Ps[(qb * 16 + cc) * PS + c * 16 + rb * 4] = p4;
      }
      rs += __shfl_xor(rs, 16);
      rs += __shfl_xor(rs, 32);
      lrow[qb] += rs;
    }
    asm volatile("s_waitcnt lgkmcnt(0)" ::: "memory");   // wave-local RAW on Ps
    __builtin_amdgcn_sched_barrier(0);                   // rule #18
    __builtin_amdgcn_s_setprio(1);
    #pragma unroll
    for (int kc = 0; kc < 2; kc++) {
      bf16x8 pF0 = *(bf16x8*)&Ps[(size_t)cc * PS + kc * 32 + rb * 8];
      bf16x8 pF1 = *(bf16x8*)&Ps[(size_t)(16 + cc) * PS + kc * 32 + rb * 8];
      #pragma unroll
      for (int d0 = 0; d0 < 4; d0++) {
        acc[0][d0] = __builtin_amdgcn_mfma_f32_16x16x32_bf16(vf[kc][d0], pF0, acc[0][d0], 0, 0, 0);
        acc[1][d0] = __builtin_amdgcn_mfma_f32_16x16x32_bf16(vf[kc][d0], pF1, acc[1][d0], 0, 0, 0);
      }
    }
    __builtin_amdgcn_s_setprio(0);
  };

  // software pipeline: sqA holds tile kt, sqB tile kt+1 (MFMAs issued early)
  loadK(0, kfA);
  qkt(kfA, sqA);
  if (nfull >= 1) loadK(1, kfB);
  for (int kt = 0; kt <= nfull; kt += 2) {
    if (kt + 1 <= nfull) qkt(kfB, sqB);          // MFMA for t+1 (overlaps below)
    if (kt + 2 <= nfull) loadK(kt + 2, kfA);     // kfA dead -> reload
    process(kt, sqA);                            // VALU softmax overlaps MFMAs
    if (kt + 1 <= nfull) {
      if (kt + 2 <= nfull) qkt(kfA, sqA);        // MFMA for t+2
      if (kt + 3 <= nfull) loadK(kt + 3, kfB);   // kfB dead -> reload
      process(kt + 1, sqB);
    }
  }

  // epilogue: normalize; all-masked rows -> uniform mean of ALL V rows
  #pragma unroll
  for (int qb = 0; qb < 2; qb++) {
    int q = q0 + qb * 16 + cc;
    bool ok = lrow[qb] > 0.f;
    float inv = ok ? 1.0f / lrow[qb] : 0.f;
    #pragma unroll
    for (int d0 = 0; d0 < 4; d0++) {
      bf16x4 o4;
      #pragma unroll
      for (int j = 0; j < 4; j++) {
        float v = ok ? acc[qb][d0][j] * inv
                     : vm[bh * DHc + d0 * 16 + rb * 4 + j] * (1.0f / Lc);
        o4[j] = (__bf16)v;
      }
      *(bf16x4*)&out[((size_t)(b * Lc + q)) * Dc + h * DHc + d0 * 16 + rb * 4] = o4;
    }
  }
}

// ---------------------------------------------------------------------------
// Launch
// ---------------------------------------------------------------------------
extern "C" void kernel_launch(void* const* d_in, const int* in_sizes, int n_in,
                              void* d_out, int out_size, void* d_ws, size_t ws_size,
                              hipStream_t stream) {
  const float* x     = (const float*)d_in[0];
  const int*   tok   = (const int*)d_in[1];
  const float* Wq    = (const float*)d_in[2];
  const float* Wk    = (const float*)d_in[3];
  const float* Wv    = (const float*)d_in[4];
  const float* Wo    = (const float*)d_in[5];
  const float* gamma = (const float*)d_in[6];
  const float* beta  = (const float*)d_in[7];
  float* out = (float*)d_out;

  const size_t SEG = (size_t)NTOK * Dc;     // 4,194,304 elems
  const size_t WSEG = (size_t)Dc * Dc;      // 262,144 elems
  u16* xn   = (u16*)d_ws;
  u16* Qd   = xn + SEG;
  u16* Kd   = Qd + SEG;
  u16* VT   = Kd + SEG;                     // blocked [B][H][L/64][DH][64]
  u16* ao   = VT + SEG;
  u16* Wqkv = ao + SEG;                     // 3*WSEG (Q,K,V rows stacked)
  u16* Wob  = Wqkv + 3 * WSEG;
  float* vm = (float*)(Wob + WSEG);         // 2048 f32
  u64* pmarr = (u64*)(vm + (size_t)Bc * Hc * DHc);  // 128 u64

  prep2_kernel<<<3104, 256, 0, stream>>>(Wq, Wk, Wv, Wo,
                                         Wqkv, Wqkv + WSEG, Wqkv + 2 * WSEG, Wob,
                                         tok, pmarr, vm, x, gamma, beta, xn);

  dim3 gq(NTOK / 128, (3 * Dc) / 128);      // 64 x 12
  gemm_bf16<3><<<gq, 256, 0, stream>>>(xn, Wqkv, nullptr, nullptr, Qd, Kd, VT, vm);

  dim3 ga(Bc * Hc, Lc / 32);                // 32 x 64 one-wave blocks
  attn13<<<ga, 64, 0, stream>>>(Qd, Kd, VT, vm, pmarr, ao);

  dim3 gg(NTOK / 128, Dc / 128);            // 64 x 4
  gemm_bf16<0><<<gg, 256, 0, stream>>>(ao, Wob, x, out, nullptr, nullptr, nullptr, nullptr);
}